// Round 3
// baseline (525.261 us; speedup 1.0000x reference)
//
#include <hip/hip_runtime.h>

// KWinnersTakeAll: x (B=4096, D=16384) fp32. k_active = 820.
// threshold = (topv[819] + topv[820]) * 0.5 (descending, 0-indexed), mask = x > thr.
// R3: no LDS row, no histogram. Fixed candidate band (TLO, THI]:
//   pass 1: read x, count a = #{x > THI}, append band values to LDS (~500/row)
//   rank:   exact tie-aware O(C^2) ranking among candidates (order-invariant)
//   pass 2: re-read x (L1/L2-hot) -> write mask
// Per-row validity check; exact bitwise radix-select fallback if band misses.

#define DDIM   16384
#define BLOCK  256
#define JCNT   (DDIM / 4 / BLOCK)   // 16 float4 iterations per thread
#define CAP    2048
#define R1     819u
#define R2     820u
#define TLO    1.50f
#define THI    1.80f

__device__ __forceinline__ unsigned f2k(float f) {
    unsigned u = __float_as_uint(f);
    return u ^ ((unsigned)((int)u >> 31) | 0x80000000u);
}
__device__ __forceinline__ float k2f(unsigned k) {
    unsigned u = (k & 0x80000000u) ? (k ^ 0x80000000u) : ~k;
    return __uint_as_float(u);
}

__global__ __launch_bounds__(BLOCK, 4)
void kwta_kernel(const float* __restrict__ x, float* __restrict__ out) {
    __shared__ float cand[CAP];                  // 8 KB
    __shared__ unsigned s_cnt;
    __shared__ unsigned s_red[BLOCK / 64];
    __shared__ unsigned s_redm[BLOCK / 64];
    __shared__ unsigned s_above, s_total;
    __shared__ int s_fallback;
    __shared__ float s_v1, s_v2;

    const int tid = threadIdx.x;
    const size_t base = (size_t)blockIdx.x * DDIM;
    const float4* __restrict__ x4 = (const float4*)(x + base);
    float4* __restrict__ o4 = (float4*)(out + base);

    if (tid == 0) s_cnt = 0u;
    __syncthreads();

    // ---- Pass 1: read row, count above-band, collect in-band candidates ----
    unsigned acnt = 0;
#pragma unroll 4
    for (int j = 0; j < JCNT; ++j) {
        float4 f = x4[j * BLOCK + tid];
        float v[4] = {f.x, f.y, f.z, f.w};
#pragma unroll
        for (int q = 0; q < 4; ++q) {
            float xv = v[q];
            acnt += (xv > THI) ? 1u : 0u;
            if (xv > TLO && xv <= THI) {
                unsigned p = atomicAdd(&s_cnt, 1u);
                if (p < CAP) cand[p] = xv;
            }
        }
    }
#pragma unroll
    for (int d = 32; d >= 1; d >>= 1) acnt += __shfl_xor(acnt, d, 64);
    if ((tid & 63) == 0) s_red[tid >> 6] = acnt;
    __syncthreads();
    if (tid == 0) {
        unsigned a = 0;
        for (int w = 0; w < BLOCK / 64; ++w) a += s_red[w];
        s_above = a;
        unsigned c = s_cnt;
        s_fallback = !(a <= R1 && a + c > R2 && c <= CAP);
    }
    __syncthreads();

    const unsigned A = s_above;
    const unsigned C = s_cnt;
    const int fb = s_fallback;

    if (!fb) {
        // ---- Exact tie-aware ranking among candidates (order-invariant) ----
        for (unsigned j = tid; j < C; j += BLOCK) {
            float xj = cand[j];
            unsigned g = 0, e = 0;
            for (unsigned i = 0; i < C; ++i) {
                float xi = cand[i];
                g += (xi > xj) ? 1u : 0u;
                e += (xi == xj) ? 1u : 0u;
            }
            unsigned lo = A + g, hi = lo + e;
            if (R1 >= lo && R1 < hi) s_v1 = xj;
            if (R2 >= lo && R2 < hi) s_v2 = xj;
        }
    } else {
        // ---- Fallback: exact bitwise radix select over the global row ----
        const float* __restrict__ xr = x + base;
        unsigned prefix = 0, r = R1;
        for (int bit = 31; bit >= 0; --bit) {
            unsigned hiMask = (bit == 31) ? 0u : ~((1u << (bit + 1)) - 1u);
            unsigned bm = 1u << bit;
            unsigned cnt = 0;
            for (int v = tid; v < DDIM; v += BLOCK) {
                unsigned k = f2k(xr[v]);
                cnt += (((k & hiMask) == prefix) && (k & bm)) ? 1u : 0u;
            }
            for (int d = 32; d >= 1; d >>= 1) cnt += __shfl_xor(cnt, d, 64);
            if ((tid & 63) == 0) s_red[tid >> 6] = cnt;
            __syncthreads();
            if (tid == 0) {
                unsigned t = 0;
                for (int w = 0; w < BLOCK / 64; ++w) t += s_red[w];
                s_total = t;
            }
            __syncthreads();
            unsigned c1 = s_total;
            if (r < c1) prefix |= bm; else r -= c1;
            __syncthreads();
        }
        unsigned K1 = prefix;
        unsigned cge = 0, mb = 0;
        for (int v = tid; v < DDIM; v += BLOCK) {
            unsigned k = f2k(xr[v]);
            if (k >= K1) cge++; else mb = mb > k ? mb : k;
        }
        for (int d = 32; d >= 1; d >>= 1) {
            cge += __shfl_xor(cge, d, 64);
            unsigned om = __shfl_xor(mb, d, 64);
            mb = mb > om ? mb : om;
        }
        if ((tid & 63) == 0) { s_red[tid >> 6] = cge; s_redm[tid >> 6] = mb; }
        __syncthreads();
        if (tid == 0) {
            unsigned t = 0, m = 0;
            for (int w = 0; w < BLOCK / 64; ++w) {
                t += s_red[w];
                m = m > s_redm[w] ? m : s_redm[w];
            }
            unsigned K2 = (t >= R2 + 1u) ? K1 : m;
            s_v1 = k2f(K1);
            s_v2 = k2f(K2);
        }
    }
    __syncthreads();

    const float thr = (s_v1 + s_v2) * 0.5f;

    // ---- Pass 2: re-read row (cache-hot), write mask ----
#pragma unroll 4
    for (int j = 0; j < JCNT; ++j) {
        float4 f = x4[j * BLOCK + tid];
        float4 m;
        m.x = (f.x > thr) ? 1.0f : 0.0f;
        m.y = (f.y > thr) ? 1.0f : 0.0f;
        m.z = (f.z > thr) ? 1.0f : 0.0f;
        m.w = (f.w > thr) ? 1.0f : 0.0f;
        o4[j * BLOCK + tid] = m;
    }
}

extern "C" void kernel_launch(void* const* d_in, const int* in_sizes, int n_in,
                              void* d_out, int out_size, void* d_ws, size_t ws_size,
                              hipStream_t stream) {
    const float* x = (const float*)d_in[0];
    float* out = (float*)d_out;
    int batch = in_sizes[0] / DDIM;
    kwta_kernel<<<batch, BLOCK, 0, stream>>>(x, out);
}

// Round 4
// 493.804 us; speedup vs baseline: 1.0637x; 1.0637x over previous
//
#include <hip/hip_runtime.h>

// KWinnersTakeAll: x (B=4096, D=16384) fp32. k_active = 820.
// threshold = (topv[819] + topv[820]) * 0.5 (descending, 0-indexed), mask = x > thr.
// R4 = R3 + fine histogram over the candidate band to kill the O(C^2) rank scan:
//   pass 1: read x; a = #{x > THI}; in-band values -> cand[] AND 256-bin hist
//   scan:   1-wave suffix scan of hist locates bins holding ranks R1-A, R2-A
//   rank:   only candidates in those bins (~2-8) do the exact tie-aware g/e scan
//   pass 2: re-read x (L3-hot) -> write mask
// Validity check per row; exact bitwise radix-select fallback if band misses.

#define DDIM   16384
#define BLOCK  256
#define JCNT   (DDIM / 4 / BLOCK)   // 16 float4 iterations per thread
#define CAP    2048
#define NB     256
#define R1     819u
#define R2     820u
#define TLO    1.50f
#define THI    1.80f
#define BSCALE (NB / (THI - TLO))   // 853.33 bins per unit

__device__ __forceinline__ unsigned f2k(float f) {
    unsigned u = __float_as_uint(f);
    return u ^ ((unsigned)((int)u >> 31) | 0x80000000u);
}
__device__ __forceinline__ float k2f(unsigned k) {
    unsigned u = (k & 0x80000000u) ? (k ^ 0x80000000u) : ~k;
    return __uint_as_float(u);
}
__device__ __forceinline__ int bandbin(float xv) {
    // monotone in xv; xv in (TLO, THI] -> [0, NB-1]
    int b = (int)floorf((xv - TLO) * BSCALE);
    return b < 0 ? 0 : (b > NB - 1 ? NB - 1 : b);
}

__global__ __launch_bounds__(BLOCK, 4)
void kwta_kernel(const float* __restrict__ x, float* __restrict__ out) {
    __shared__ float cand[CAP];                  // 8 KB
    __shared__ unsigned hist[NB];                // 1 KB
    __shared__ unsigned s_cnt;
    __shared__ unsigned s_red[BLOCK / 64];
    __shared__ unsigned s_redm[BLOCK / 64];
    __shared__ unsigned s_above, s_total;
    __shared__ int s_fallback, s_b1, s_b2;
    __shared__ float s_v1, s_v2;

    const int tid = threadIdx.x;
    const size_t base = (size_t)blockIdx.x * DDIM;
    const float4* __restrict__ x4 = (const float4*)(x + base);
    float4* __restrict__ o4 = (float4*)(out + base);

    hist[tid] = 0u;
    if (tid == 0) s_cnt = 0u;
    __syncthreads();

    // ---- Pass 1: read row, count above-band, collect + histogram in-band ----
    unsigned acnt = 0;
#pragma unroll 4
    for (int j = 0; j < JCNT; ++j) {
        float4 f = x4[j * BLOCK + tid];
        float v[4] = {f.x, f.y, f.z, f.w};
#pragma unroll
        for (int q = 0; q < 4; ++q) {
            float xv = v[q];
            acnt += (xv > THI) ? 1u : 0u;
            if (xv > TLO && xv <= THI) {
                unsigned p = atomicAdd(&s_cnt, 1u);
                if (p < CAP) cand[p] = xv;
                atomicAdd(&hist[bandbin(xv)], 1u);
            }
        }
    }
#pragma unroll
    for (int d = 32; d >= 1; d >>= 1) acnt += __shfl_xor(acnt, d, 64);
    if ((tid & 63) == 0) s_red[tid >> 6] = acnt;
    __syncthreads();
    if (tid == 0) {
        unsigned a = 0;
        for (int w = 0; w < BLOCK / 64; ++w) a += s_red[w];
        s_above = a;
        unsigned c = s_cnt;
        s_fallback = !(a <= R1 && a + c > R2 && c <= CAP);
    }
    __syncthreads();

    const unsigned A = s_above;
    const unsigned C = s_cnt;
    const int fb = s_fallback;

    if (!fb) {
        // ---- Locate hist bins holding band-relative ranks R1-A, R2-A ----
        if (tid < 64) {
            const unsigned r1p = R1 - A, r2p = R2 - A;
            int c = tid;
            int top = (NB - 1) - (c << 2);    // chunk: bins [top-3, top]
            unsigned s = 0;
#pragma unroll
            for (int i = 0; i < 4; ++i) s += hist[top - i];
            unsigned v = s;
#pragma unroll
            for (int d = 1; d < 64; d <<= 1) {
                unsigned u = __shfl_up(v, d, 64);
                if (c >= d) v += u;
            }
            unsigned cum = v - s;             // in-band count above this chunk
#pragma unroll
            for (int i = 0; i < 4; ++i) {
                unsigned h = hist[top - i];
                if (r1p >= cum && r1p < cum + h) s_b1 = top - i;
                if (r2p >= cum && r2p < cum + h) s_b2 = top - i;
                cum += h;
            }
        }
        __syncthreads();
        const int b1 = s_b1, b2 = s_b2;

        // ---- Exact tie-aware ranking, restricted to target bins ----
        for (unsigned j = tid; j < C; j += BLOCK) {
            float xj = cand[j];
            int b = bandbin(xj);
            if (b >= b2 && b <= b1) {
                unsigned g = 0, e = 0;
                for (unsigned i = 0; i < C; ++i) {
                    float xi = cand[i];
                    g += (xi > xj) ? 1u : 0u;
                    e += (xi == xj) ? 1u : 0u;
                }
                unsigned lo = A + g, hi = lo + e;
                if (R1 >= lo && R1 < hi) s_v1 = xj;
                if (R2 >= lo && R2 < hi) s_v2 = xj;
            }
        }
    } else {
        // ---- Fallback: exact bitwise radix select over the global row ----
        const float* __restrict__ xr = x + base;
        unsigned prefix = 0, r = R1;
        for (int bit = 31; bit >= 0; --bit) {
            unsigned hiMask = (bit == 31) ? 0u : ~((1u << (bit + 1)) - 1u);
            unsigned bm = 1u << bit;
            unsigned cnt = 0;
            for (int v = tid; v < DDIM; v += BLOCK) {
                unsigned k = f2k(xr[v]);
                cnt += (((k & hiMask) == prefix) && (k & bm)) ? 1u : 0u;
            }
            for (int d = 32; d >= 1; d >>= 1) cnt += __shfl_xor(cnt, d, 64);
            if ((tid & 63) == 0) s_red[tid >> 6] = cnt;
            __syncthreads();
            if (tid == 0) {
                unsigned t = 0;
                for (int w = 0; w < BLOCK / 64; ++w) t += s_red[w];
                s_total = t;
            }
            __syncthreads();
            unsigned c1 = s_total;
            if (r < c1) prefix |= bm; else r -= c1;
            __syncthreads();
        }
        unsigned K1 = prefix;
        unsigned cge = 0, mb = 0;
        for (int v = tid; v < DDIM; v += BLOCK) {
            unsigned k = f2k(xr[v]);
            if (k >= K1) cge++; else mb = mb > k ? mb : k;
        }
        for (int d = 32; d >= 1; d >>= 1) {
            cge += __shfl_xor(cge, d, 64);
            unsigned om = __shfl_xor(mb, d, 64);
            mb = mb > om ? mb : om;
        }
        if ((tid & 63) == 0) { s_red[tid >> 6] = cge; s_redm[tid >> 6] = mb; }
        __syncthreads();
        if (tid == 0) {
            unsigned t = 0, m = 0;
            for (int w = 0; w < BLOCK / 64; ++w) {
                t += s_red[w];
                m = m > s_redm[w] ? m : s_redm[w];
            }
            unsigned K2 = (t >= R2 + 1u) ? K1 : m;
            s_v1 = k2f(K1);
            s_v2 = k2f(K2);
        }
    }
    __syncthreads();

    const float thr = (s_v1 + s_v2) * 0.5f;

    // ---- Pass 2: re-read row (L3-hot), write mask ----
#pragma unroll 4
    for (int j = 0; j < JCNT; ++j) {
        float4 f = x4[j * BLOCK + tid];
        float4 m;
        m.x = (f.x > thr) ? 1.0f : 0.0f;
        m.y = (f.y > thr) ? 1.0f : 0.0f;
        m.z = (f.z > thr) ? 1.0f : 0.0f;
        m.w = (f.w > thr) ? 1.0f : 0.0f;
        o4[j * BLOCK + tid] = m;
    }
}

extern "C" void kernel_launch(void* const* d_in, const int* in_sizes, int n_in,
                              void* d_out, int out_size, void* d_ws, size_t ws_size,
                              hipStream_t stream) {
    const float* x = (const float*)d_in[0];
    float* out = (float*)d_out;
    int batch = in_sizes[0] / DDIM;
    kwta_kernel<<<batch, BLOCK, 0, stream>>>(x, out);
}

// Round 5
// 484.469 us; speedup vs baseline: 1.0842x; 1.0193x over previous
//
#include <hip/hip_runtime.h>

// KWinnersTakeAll: x (B=4096, D=16384) fp32. k_active = 820.
// threshold = (topv[819] + topv[820]) * 0.5 (descending, 0-indexed), mask = x > thr.
// R5: single global read, single global write. Since thr is proven to lie in
// (TLO, THI], elements > THI are certainly 1 and <= TLO certainly 0 -> pass 1
// writes a byte-packed provisional mask into LDS and collects the ~500
// uncertain in-band (value, idx) pairs. Histogram ranking (R4) finds the two
// rank values; a ~250-atomicOr patch fixes in-band bytes; pass 2 expands the
// LDS mask to float4 stores. Exact radix-select fallback re-reads x globally.

#define DDIM   16384
#define BLOCK  256
#define JCNT   (DDIM / 4 / BLOCK)   // 16 float4 iterations per thread
#define CAP    1024
#define NB     256
#define R1     819u
#define R2     820u
#define TLO    1.50f
#define THI    1.80f
#define BSCALE (NB / (THI - TLO))   // 853.33 bins per unit

__device__ __forceinline__ unsigned f2k(float f) {
    unsigned u = __float_as_uint(f);
    return u ^ ((unsigned)((int)u >> 31) | 0x80000000u);
}
__device__ __forceinline__ float k2f(unsigned k) {
    unsigned u = (k & 0x80000000u) ? (k ^ 0x80000000u) : ~k;
    return __uint_as_float(u);
}
__device__ __forceinline__ int bandbin(float xv) {
    int b = (int)floorf((xv - TLO) * BSCALE);
    return b < 0 ? 0 : (b > NB - 1 ? NB - 1 : b);
}

__global__ __launch_bounds__(BLOCK, 4)
void kwta_kernel(const float* __restrict__ x, float* __restrict__ out) {
    __shared__ unsigned maskW[DDIM / 4];         // 16 KB byte-packed mask
    __shared__ float candV[CAP];                 // 4 KB
    __shared__ unsigned short candI[CAP];        // 2 KB
    __shared__ unsigned hist[NB];                // 1 KB
    __shared__ unsigned s_cnt;
    __shared__ unsigned s_red[BLOCK / 64];
    __shared__ unsigned s_redm[BLOCK / 64];
    __shared__ unsigned s_above, s_total;
    __shared__ int s_fallback, s_b1, s_b2;
    __shared__ float s_v1, s_v2;

    const int tid = threadIdx.x;
    const size_t base = (size_t)blockIdx.x * DDIM;
    const float4* __restrict__ x4 = (const float4*)(x + base);
    float4* __restrict__ o4 = (float4*)(out + base);

    hist[tid] = 0u;
    if (tid == 0) s_cnt = 0u;
    __syncthreads();

    // ---- Pass 1: single global read; provisional mask -> LDS; collect band ----
    unsigned acnt = 0;
#pragma unroll 4
    for (int j = 0; j < JCNT; ++j) {
        const int v = j * BLOCK + tid;
        float4 f = x4[v];
        float vv[4] = {f.x, f.y, f.z, f.w};
        unsigned w = 0;
#pragma unroll
        for (int q = 0; q < 4; ++q) {
            float xv = vv[q];
            unsigned hi = (xv > THI) ? 1u : 0u;
            acnt += hi;
            w |= hi << (q * 8);
            if (xv > TLO && xv <= THI) {
                unsigned p = atomicAdd(&s_cnt, 1u);
                if (p < CAP) { candV[p] = xv; candI[p] = (unsigned short)(4 * v + q); }
                atomicAdd(&hist[bandbin(xv)], 1u);
            }
        }
        maskW[v] = w;
    }
#pragma unroll
    for (int d = 32; d >= 1; d >>= 1) acnt += __shfl_xor(acnt, d, 64);
    if ((tid & 63) == 0) s_red[tid >> 6] = acnt;
    __syncthreads();
    if (tid == 0) {
        unsigned a = 0;
        for (int w = 0; w < BLOCK / 64; ++w) a += s_red[w];
        s_above = a;
        unsigned c = s_cnt;
        s_fallback = !(a <= R1 && a + c > R2 && c <= CAP);
    }
    __syncthreads();

    const unsigned A = s_above;
    const unsigned C = s_cnt;
    const int fb = s_fallback;

    if (!fb) {
        // ---- Locate hist bins holding band-relative ranks R1-A, R2-A ----
        if (tid < 64) {
            const unsigned r1p = R1 - A, r2p = R2 - A;
            int c = tid;
            int top = (NB - 1) - (c << 2);    // chunk: bins [top-3, top]
            unsigned s = 0;
#pragma unroll
            for (int i = 0; i < 4; ++i) s += hist[top - i];
            unsigned v = s;
#pragma unroll
            for (int d = 1; d < 64; d <<= 1) {
                unsigned u = __shfl_up(v, d, 64);
                if (c >= d) v += u;
            }
            unsigned cum = v - s;             // in-band count above this chunk
#pragma unroll
            for (int i = 0; i < 4; ++i) {
                unsigned h = hist[top - i];
                if (r1p >= cum && r1p < cum + h) s_b1 = top - i;
                if (r2p >= cum && r2p < cum + h) s_b2 = top - i;
                cum += h;
            }
        }
        __syncthreads();
        const int b1 = s_b1, b2 = s_b2;

        // ---- Exact tie-aware ranking, restricted to target bins ----
        for (unsigned j = tid; j < C; j += BLOCK) {
            float xj = candV[j];
            int b = bandbin(xj);
            if (b >= b2 && b <= b1) {
                unsigned g = 0, e = 0;
                for (unsigned i = 0; i < C; ++i) {
                    float xi = candV[i];
                    g += (xi > xj) ? 1u : 0u;
                    e += (xi == xj) ? 1u : 0u;
                }
                unsigned lo = A + g, hi = lo + e;
                if (R1 >= lo && R1 < hi) s_v1 = xj;
                if (R2 >= lo && R2 < hi) s_v2 = xj;
            }
        }
        __syncthreads();

        const float thr = (s_v1 + s_v2) * 0.5f;

        // ---- Patch in-band bytes in the LDS mask ----
        for (unsigned p = tid; p < C; p += BLOCK) {
            if (candV[p] > thr) {
                unsigned e = candI[p];
                atomicOr(&maskW[e >> 2], 1u << ((e & 3u) * 8u));
            }
        }
        __syncthreads();

        // ---- Pass 2: expand LDS mask -> global float4 stores ----
#pragma unroll 4
        for (int j = 0; j < JCNT; ++j) {
            const int v = j * BLOCK + tid;
            unsigned w = maskW[v];
            float4 m;
            m.x = (w & 0x000000FFu) ? 1.0f : 0.0f;
            m.y = (w & 0x0000FF00u) ? 1.0f : 0.0f;
            m.z = (w & 0x00FF0000u) ? 1.0f : 0.0f;
            m.w = (w & 0xFF000000u) ? 1.0f : 0.0f;
            o4[v] = m;
        }
    } else {
        // ---- Fallback: exact bitwise radix select over the global row ----
        const float* __restrict__ xr = x + base;
        unsigned prefix = 0, r = R1;
        for (int bit = 31; bit >= 0; --bit) {
            unsigned hiMask = (bit == 31) ? 0u : ~((1u << (bit + 1)) - 1u);
            unsigned bm = 1u << bit;
            unsigned cnt = 0;
            for (int v = tid; v < DDIM; v += BLOCK) {
                unsigned k = f2k(xr[v]);
                cnt += (((k & hiMask) == prefix) && (k & bm)) ? 1u : 0u;
            }
            for (int d = 32; d >= 1; d >>= 1) cnt += __shfl_xor(cnt, d, 64);
            if ((tid & 63) == 0) s_red[tid >> 6] = cnt;
            __syncthreads();
            if (tid == 0) {
                unsigned t = 0;
                for (int w = 0; w < BLOCK / 64; ++w) t += s_red[w];
                s_total = t;
            }
            __syncthreads();
            unsigned c1 = s_total;
            if (r < c1) prefix |= bm; else r -= c1;
            __syncthreads();
        }
        unsigned K1 = prefix;
        unsigned cge = 0, mb = 0;
        for (int v = tid; v < DDIM; v += BLOCK) {
            unsigned k = f2k(xr[v]);
            if (k >= K1) cge++; else mb = mb > k ? mb : k;
        }
        for (int d = 32; d >= 1; d >>= 1) {
            cge += __shfl_xor(cge, d, 64);
            unsigned om = __shfl_xor(mb, d, 64);
            mb = mb > om ? mb : om;
        }
        if ((tid & 63) == 0) { s_red[tid >> 6] = cge; s_redm[tid >> 6] = mb; }
        __syncthreads();
        if (tid == 0) {
            unsigned t = 0, m = 0;
            for (int w = 0; w < BLOCK / 64; ++w) {
                t += s_red[w];
                m = m > s_redm[w] ? m : s_redm[w];
            }
            unsigned K2 = (t >= R2 + 1u) ? K1 : m;
            s_v1 = k2f(K1);
            s_v2 = k2f(K2);
        }
        __syncthreads();

        const float thr = (s_v1 + s_v2) * 0.5f;
#pragma unroll 4
        for (int j = 0; j < JCNT; ++j) {
            const int v = j * BLOCK + tid;
            float4 f = x4[v];
            float4 m;
            m.x = (f.x > thr) ? 1.0f : 0.0f;
            m.y = (f.y > thr) ? 1.0f : 0.0f;
            m.z = (f.z > thr) ? 1.0f : 0.0f;
            m.w = (f.w > thr) ? 1.0f : 0.0f;
            o4[v] = m;
        }
    }
}

extern "C" void kernel_launch(void* const* d_in, const int* in_sizes, int n_in,
                              void* d_out, int out_size, void* d_ws, size_t ws_size,
                              hipStream_t stream) {
    const float* x = (const float*)d_in[0];
    float* out = (float*)d_out;
    int batch = in_sizes[0] / DDIM;
    kwta_kernel<<<batch, BLOCK, 0, stream>>>(x, out);
}

// Round 6
// 481.119 us; speedup vs baseline: 1.0917x; 1.0070x over previous
//
#include <hip/hip_runtime.h>

// KWinnersTakeAll: x (B=4096, D=16384) fp32. k_active = 820.
// threshold = (topv[819] + topv[820]) * 0.5 (descending, 0-indexed), mask = x > thr.
// R6 = R5 with a BIT-packed provisional mask (2 KB instead of 16 KB bytes):
//   LDS ~9.3 KB -> 8 blocks/CU (wave cap) instead of 6, more phase overlap.
//   Pass 1: read x once; certain bits (x>THI -> 1, x<=TLO -> 0) packed via
//   3x shfl_xor or-reduce per 8-lane group; ~500 in-band (val,idx) -> LDS.
//   Histogram ranking (proven R4/R5) -> thr; ~250 atomicOr bit patches;
//   expansion pass: LDS bits -> float4 stores. Radix-select fallback intact.

#define DDIM   16384
#define BLOCK  256
#define JCNT   (DDIM / 4 / BLOCK)   // 16 float4 iterations per thread
#define CAP    1024
#define NB     256
#define R1     819u
#define R2     820u
#define TLO    1.50f
#define THI    1.80f
#define BSCALE (NB / (THI - TLO))   // 853.33 bins per unit

__device__ __forceinline__ unsigned f2k(float f) {
    unsigned u = __float_as_uint(f);
    return u ^ ((unsigned)((int)u >> 31) | 0x80000000u);
}
__device__ __forceinline__ float k2f(unsigned k) {
    unsigned u = (k & 0x80000000u) ? (k ^ 0x80000000u) : ~k;
    return __uint_as_float(u);
}
__device__ __forceinline__ int bandbin(float xv) {
    int b = (int)floorf((xv - TLO) * BSCALE);
    return b < 0 ? 0 : (b > NB - 1 ? NB - 1 : b);
}

__global__ __launch_bounds__(BLOCK, 8)
void kwta_kernel(const float* __restrict__ x, float* __restrict__ out) {
    __shared__ unsigned maskBits[DDIM / 32];     // 2 KB: 1 bit per element
    __shared__ float candV[CAP];                 // 4 KB
    __shared__ unsigned short candI[CAP];        // 2 KB
    __shared__ unsigned hist[NB];                // 1 KB
    __shared__ unsigned s_cnt;
    __shared__ unsigned s_red[BLOCK / 64];
    __shared__ unsigned s_redm[BLOCK / 64];
    __shared__ unsigned s_above, s_total;
    __shared__ int s_fallback, s_b1, s_b2;
    __shared__ float s_v1, s_v2;

    const int tid = threadIdx.x;
    const size_t base = (size_t)blockIdx.x * DDIM;
    const float4* __restrict__ x4 = (const float4*)(x + base);
    float4* __restrict__ o4 = (float4*)(out + base);

    hist[tid] = 0u;
    if (tid == 0) s_cnt = 0u;
    __syncthreads();

    // ---- Pass 1: single global read; provisional bit-mask; collect band ----
    const int grp = tid & 7;            // position within the 8-lane word group
    unsigned acnt = 0;
#pragma unroll 4
    for (int j = 0; j < JCNT; ++j) {
        const int v = j * BLOCK + tid;
        float4 f = x4[v];
        float vv[4] = {f.x, f.y, f.z, f.w};
        unsigned nib = 0;
#pragma unroll
        for (int q = 0; q < 4; ++q) {
            float xv = vv[q];
            unsigned hi = (xv > THI) ? 1u : 0u;
            acnt += hi;
            nib |= hi << q;
            if (xv > TLO && xv <= THI) {
                unsigned p = atomicAdd(&s_cnt, 1u);
                if (p < CAP) { candV[p] = xv; candI[p] = (unsigned short)(4 * v + q); }
                atomicAdd(&hist[bandbin(xv)], 1u);
            }
        }
        unsigned w = nib << (grp * 4);
        w |= __shfl_xor(w, 1, 64);
        w |= __shfl_xor(w, 2, 64);
        w |= __shfl_xor(w, 4, 64);
        if (grp == 0) maskBits[j * (BLOCK / 8) + (tid >> 3)] = w;
    }
#pragma unroll
    for (int d = 32; d >= 1; d >>= 1) acnt += __shfl_xor(acnt, d, 64);
    if ((tid & 63) == 0) s_red[tid >> 6] = acnt;
    __syncthreads();
    if (tid == 0) {
        unsigned a = 0;
        for (int w = 0; w < BLOCK / 64; ++w) a += s_red[w];
        s_above = a;
        unsigned c = s_cnt;
        s_fallback = !(a <= R1 && a + c > R2 && c <= CAP);
    }
    __syncthreads();

    const unsigned A = s_above;
    const unsigned C = s_cnt;
    const int fb = s_fallback;

    if (!fb) {
        // ---- Locate hist bins holding band-relative ranks R1-A, R2-A ----
        if (tid < 64) {
            const unsigned r1p = R1 - A, r2p = R2 - A;
            int c = tid;
            int top = (NB - 1) - (c << 2);    // chunk: bins [top-3, top]
            unsigned s = 0;
#pragma unroll
            for (int i = 0; i < 4; ++i) s += hist[top - i];
            unsigned v = s;
#pragma unroll
            for (int d = 1; d < 64; d <<= 1) {
                unsigned u = __shfl_up(v, d, 64);
                if (c >= d) v += u;
            }
            unsigned cum = v - s;             // in-band count above this chunk
#pragma unroll
            for (int i = 0; i < 4; ++i) {
                unsigned h = hist[top - i];
                if (r1p >= cum && r1p < cum + h) s_b1 = top - i;
                if (r2p >= cum && r2p < cum + h) s_b2 = top - i;
                cum += h;
            }
        }
        __syncthreads();
        const int b1 = s_b1, b2 = s_b2;

        // ---- Exact tie-aware ranking, restricted to target bins ----
        for (unsigned j = tid; j < C; j += BLOCK) {
            float xj = candV[j];
            int b = bandbin(xj);
            if (b >= b2 && b <= b1) {
                unsigned g = 0, e = 0;
                for (unsigned i = 0; i < C; ++i) {
                    float xi = candV[i];
                    g += (xi > xj) ? 1u : 0u;
                    e += (xi == xj) ? 1u : 0u;
                }
                unsigned lo = A + g, hi = lo + e;
                if (R1 >= lo && R1 < hi) s_v1 = xj;
                if (R2 >= lo && R2 < hi) s_v2 = xj;
            }
        }
        __syncthreads();

        const float thr = (s_v1 + s_v2) * 0.5f;

        // ---- Patch in-band winners into the LDS bit-mask ----
        for (unsigned p = tid; p < C; p += BLOCK) {
            if (candV[p] > thr) {
                unsigned e = candI[p];
                atomicOr(&maskBits[e >> 5], 1u << (e & 31u));
            }
        }
        __syncthreads();

        // ---- Pass 2: expand LDS bits -> global float4 stores ----
#pragma unroll 4
        for (int j = 0; j < JCNT; ++j) {
            const int v = j * BLOCK + tid;
            unsigned w = maskBits[j * (BLOCK / 8) + (tid >> 3)];
            unsigned nib = (w >> (grp * 4)) & 0xFu;
            float4 m;
            m.x = (nib & 1u) ? 1.0f : 0.0f;
            m.y = (nib & 2u) ? 1.0f : 0.0f;
            m.z = (nib & 4u) ? 1.0f : 0.0f;
            m.w = (nib & 8u) ? 1.0f : 0.0f;
            o4[v] = m;
        }
    } else {
        // ---- Fallback: exact bitwise radix select over the global row ----
        const float* __restrict__ xr = x + base;
        unsigned prefix = 0, r = R1;
        for (int bit = 31; bit >= 0; --bit) {
            unsigned hiMask = (bit == 31) ? 0u : ~((1u << (bit + 1)) - 1u);
            unsigned bm = 1u << bit;
            unsigned cnt = 0;
            for (int v = tid; v < DDIM; v += BLOCK) {
                unsigned k = f2k(xr[v]);
                cnt += (((k & hiMask) == prefix) && (k & bm)) ? 1u : 0u;
            }
            for (int d = 32; d >= 1; d >>= 1) cnt += __shfl_xor(cnt, d, 64);
            if ((tid & 63) == 0) s_red[tid >> 6] = cnt;
            __syncthreads();
            if (tid == 0) {
                unsigned t = 0;
                for (int w = 0; w < BLOCK / 64; ++w) t += s_red[w];
                s_total = t;
            }
            __syncthreads();
            unsigned c1 = s_total;
            if (r < c1) prefix |= bm; else r -= c1;
            __syncthreads();
        }
        unsigned K1 = prefix;
        unsigned cge = 0, mb = 0;
        for (int v = tid; v < DDIM; v += BLOCK) {
            unsigned k = f2k(xr[v]);
            if (k >= K1) cge++; else mb = mb > k ? mb : k;
        }
        for (int d = 32; d >= 1; d >>= 1) {
            cge += __shfl_xor(cge, d, 64);
            unsigned om = __shfl_xor(mb, d, 64);
            mb = mb > om ? mb : om;
        }
        if ((tid & 63) == 0) { s_red[tid >> 6] = cge; s_redm[tid >> 6] = mb; }
        __syncthreads();
        if (tid == 0) {
            unsigned t = 0, m = 0;
            for (int w = 0; w < BLOCK / 64; ++w) {
                t += s_red[w];
                m = m > s_redm[w] ? m : s_redm[w];
            }
            unsigned K2 = (t >= R2 + 1u) ? K1 : m;
            s_v1 = k2f(K1);
            s_v2 = k2f(K2);
        }
        __syncthreads();

        const float thr = (s_v1 + s_v2) * 0.5f;
#pragma unroll 4
        for (int j = 0; j < JCNT; ++j) {
            const int v = j * BLOCK + tid;
            float4 f = x4[v];
            float4 m;
            m.x = (f.x > thr) ? 1.0f : 0.0f;
            m.y = (f.y > thr) ? 1.0f : 0.0f;
            m.z = (f.z > thr) ? 1.0f : 0.0f;
            m.w = (f.w > thr) ? 1.0f : 0.0f;
            o4[v] = m;
        }
    }
}

extern "C" void kernel_launch(void* const* d_in, const int* in_sizes, int n_in,
                              void* d_out, int out_size, void* d_ws, size_t ws_size,
                              hipStream_t stream) {
    const float* x = (const float*)d_in[0];
    float* out = (float*)d_out;
    int batch = in_sizes[0] / DDIM;
    kwta_kernel<<<batch, BLOCK, 0, stream>>>(x, out);
}